// Round 5
// baseline (229.266 us; speedup 1.0000x reference)
//
#include <hip/hip_runtime.h>
#include <hip/hip_bf16.h>

#define F_ 16384
#define D_ 768
#define C_ 16
#define BS_ 512
#define M_ (F_*C_)
#define NCHUNK 8
#define CDIM 96           // dims per chunk (NCHUNK*CDIM = D_)
#define CPB 512           // connections per k_values block
#define FPB (CPB/C_)      // 32 features per block

static __device__ __forceinline__ float bf2f(unsigned short u) {
    return __uint_as_float(((unsigned int)u) << 16);
}
static __device__ __forceinline__ unsigned short f2bf(float f) {
    return __bfloat16_as_ushort(__float2bfloat16(f));
}

// ---------------------------------------------------------------------------
// Transpose + downconvert: up_decoder fp32 [D, F] -> decC bf16 chunk-major
// [NCHUNK][F][CDIM]:  decC[c][j][dl] = dec[c*96+dl][j].
// ---------------------------------------------------------------------------
__global__ __launch_bounds__(256) void k_transpose_chunked(const float* __restrict__ in,
                                                           unsigned short* __restrict__ decC) {
    __shared__ float tile[64][65];      // [d_local][f_local], +1 pad
    int c4 = threadIdx.x & 15;          // float4 column (f)
    int r  = threadIdx.x >> 4;          // 0..15 (d)
    int fbase = blockIdx.x * 64;
    int dbase = blockIdx.y * 64;
#pragma unroll
    for (int k = 0; k < 4; ++k) {
        int drow = r + k * 16;
        float4 v = *(const float4*)(in + (size_t)(dbase + drow) * F_ + fbase + c4 * 4);
        tile[drow][c4 * 4 + 0] = v.x;
        tile[drow][c4 * 4 + 1] = v.y;
        tile[drow][c4 * 4 + 2] = v.z;
        tile[drow][c4 * 4 + 3] = v.w;
    }
    __syncthreads();
    int dp = threadIdx.x & 15;          // 4-dim group index within 64 dcols
    int fr = threadIdx.x >> 4;          // 0..15 (f)
#pragma unroll
    for (int k = 0; k < 4; ++k) {
        int frow = fr + k * 16;
        float v0 = tile[4 * dp + 0][frow];
        float v1 = tile[4 * dp + 1][frow];
        float v2 = tile[4 * dp + 2][frow];
        float v3 = tile[4 * dp + 3][frow];
        uint2 p;
        p.x = ((unsigned int)f2bf(v1) << 16) | (unsigned int)f2bf(v0);
        p.y = ((unsigned int)f2bf(v3) << 16) | (unsigned int)f2bf(v2);
        int d  = dbase + dp * 4;
        int c  = d / CDIM;
        int dl = d - c * CDIM;
        *(uint2*)(decC + ((size_t)c * F_ + (fbase + frow)) * CDIM + dl) = p;
    }
}

// ---------------------------------------------------------------------------
// Chunked values, MLP-tuned. partial[c][m] = dot(enc[f(m),c*96..+96),
// decC[c][j(m)]). blockIdx&7 = chunk (XCD-affine). 512 connections/block,
// enc slice staged as bf16 (6 KB LDS). 8-lane group per connection, 12 dims
// per lane: one uint4 + one uint2 gather. Depth-2 pipeline: gathers for
// iters i+1, i+2 in flight while computing iter i.
// ---------------------------------------------------------------------------
#define ACC2(e, g) {                                                         \
    acc += __uint_as_float((e) << 16)        * __uint_as_float((g) << 16);   \
    acc += __uint_as_float((e) & 0xffff0000u) * __uint_as_float((g) & 0xffff0000u); }

__global__ __launch_bounds__(256, 8) void k_values_chunked(const float* __restrict__ enc,
                                                           const unsigned short* __restrict__ decC,
                                                           const int* __restrict__ jidx,
                                                           float* __restrict__ partial) {
    __shared__ unsigned short encS[FPB * CDIM];   // 32 x 96 bf16 = 6 KB
    int chunk = blockIdx.x & 7;
    int mblk  = blockIdx.x >> 3;
    int m0 = mblk * CPB;
    int f0 = mblk * FPB;

    // Stage enc[f0..f0+32)[chunk*96..+96) fp32 -> bf16 LDS.
    {
        const float* eb = enc + (size_t)f0 * D_ + chunk * CDIM;
#pragma unroll
        for (int k = 0; k < 3; ++k) {
            int idx = threadIdx.x + k * 256;     // 768 float4 slots = 32 rows x 24
            int row = idx / 24;
            int col = idx - row * 24;
            float4 v = *(const float4*)(eb + (size_t)row * D_ + col * 4);
            uint2 p;
            p.x = ((unsigned int)f2bf(v.y) << 16) | (unsigned int)f2bf(v.x);
            p.y = ((unsigned int)f2bf(v.w) << 16) | (unsigned int)f2bf(v.z);
            *(uint2*)(encS + row * CDIM + col * 4) = p;
        }
    }
    __syncthreads();

    int lane = threadIdx.x & 63;
    int w    = threadIdx.x >> 6;        // wave 0..3
    int sub  = lane & 7;                // dim-group within connection
    int cg   = lane >> 3;               // connection within wave-iter
    const unsigned short* db = decC + (size_t)chunk * F_ * CDIM;

    // Prologue: gathers for iters 0 and 1; j for iter 2.
    int j0 = jidx[m0 + ((0 * 4 + w) << 3) + cg];
    int j1 = jidx[m0 + ((1 * 4 + w) << 3) + cg];
    int j2 = jidx[m0 + ((2 * 4 + w) << 3) + cg];
    const char* p0 = (const char*)(db + (size_t)j0 * CDIM) + sub * 24;
    uint4 a0 = *(const uint4*)p0;
    uint2 b0 = *(const uint2*)(p0 + 16);
    const char* p1 = (const char*)(db + (size_t)j1 * CDIM) + sub * 24;
    uint4 a1 = *(const uint4*)p1;
    uint2 b1 = *(const uint2*)(p1 + 16);

#pragma unroll 4
    for (int i = 0; i < 16; ++i) {
        uint4 an; uint2 bn;
        if (i + 2 < 16) {
            const char* pn = (const char*)(db + (size_t)j2 * CDIM) + sub * 24;
            an = *(const uint4*)pn;
            bn = *(const uint2*)(pn + 16);
        }
        if (i + 3 < 16)
            j2 = jidx[m0 + (((i + 3) * 4 + w) << 3) + cg];

        int q  = i * 4 + w;                    // 0..63
        int fl = q >> 1;                       // f_local 0..31
        const unsigned short* ep = encS + fl * CDIM + sub * 12;
        uint2 e0 = *(const uint2*)ep;          // dims 0-3
        uint2 e1 = *(const uint2*)(ep + 4);    // dims 4-7
        uint2 e2 = *(const uint2*)(ep + 8);    // dims 8-11
        float acc = 0.f;
        ACC2(e0.x, a0.x) ACC2(e0.y, a0.y)
        ACC2(e1.x, a0.z) ACC2(e1.y, a0.w)
        ACC2(e2.x, b0.x) ACC2(e2.y, b0.y)
        acc += __shfl_xor(acc, 1, 64);
        acc += __shfl_xor(acc, 2, 64);
        acc += __shfl_xor(acc, 4, 64);
        if (sub == 0)
            partial[(size_t)chunk * M_ + m0 + (q << 3) + cg] = acc;
        a0 = a1; b0 = b1; a1 = an; b1 = bn;
    }
}

// ---------------------------------------------------------------------------
// Sum the 8 chunk-partials and emit packed stream: (bf16 value << 16) | u16 j.
// ---------------------------------------------------------------------------
__global__ __launch_bounds__(256) void k_pack(const float* __restrict__ partial,
                                              const int* __restrict__ jidx,
                                              unsigned int* __restrict__ packed) {
    int m = blockIdx.x * 256 + threadIdx.x;
    float s = 0.f;
#pragma unroll
    for (int c = 0; c < NCHUNK; ++c)
        s += partial[(size_t)c * M_ + m];
    packed[m] = ((unsigned int)f2bf(s) << 16) | (unsigned int)jidx[m];
}

// ---------------------------------------------------------------------------
// out[bs,f] = sum over 16 connections of up[bs,j]*v.
// Block = (bs pair, f half): 512 blocks x 1024 threads, 64 KB LDS
// -> 2 blocks/CU = 32 waves/CU. Pair's rows staged interleaved as bf16 in
// one 4 B LDS word (one ds_read_b32 serves both rows). Index swizzle puts
// both halves of a pair on the same XCD (round-robin dispatch heuristic).
// ---------------------------------------------------------------------------
__global__ __launch_bounds__(1024) void k_out(const float* __restrict__ up,
                                              const unsigned int* __restrict__ packed,
                                              float* __restrict__ out) {
    __shared__ unsigned int rowp[F_];   // 64 KB
    int x    = blockIdx.x;
    int pair = ((x >> 4) << 3) | (x & 7);   // 0..255; halves share XCD
    int half = (x >> 3) & 1;
    int bs0  = pair << 1;
    const float4* u0 = (const float4*)(up + (size_t)bs0 * F_);
    const float4* u1 = (const float4*)(up + (size_t)(bs0 + 1) * F_);
#pragma unroll
    for (int k = 0; k < 4; ++k) {
        int idx = threadIdx.x + k * 1024;      // float4 index, 4096 total
        float4 a = u0[idx];
        float4 b = u1[idx];
        uint4 p;
        p.x = ((unsigned int)f2bf(b.x) << 16) | (unsigned int)f2bf(a.x);
        p.y = ((unsigned int)f2bf(b.y) << 16) | (unsigned int)f2bf(a.y);
        p.z = ((unsigned int)f2bf(b.z) << 16) | (unsigned int)f2bf(a.z);
        p.w = ((unsigned int)f2bf(b.w) << 16) | (unsigned int)f2bf(a.w);
        ((uint4*)rowp)[idx] = p;
    }
    __syncthreads();
    int f0 = half << 13;                       // 0 or 8192
#pragma unroll 2
    for (int it = 0; it < 8; ++it) {
        int f = f0 + threadIdx.x + it * 1024;
        const uint4* sp = (const uint4*)(packed + ((size_t)f << 4));
        float a0 = 0.f, a1 = 0.f;
#pragma unroll
        for (int q = 0; q < 4; ++q) {
            uint4 wv = sp[q];
#define CONN(ww) { unsigned int p_ = rowp[(ww) & 0xffffu];                  \
                   float v_ = __uint_as_float((ww) & 0xffff0000u);          \
                   a0 += __uint_as_float(p_ << 16) * v_;                    \
                   a1 += __uint_as_float(p_ & 0xffff0000u) * v_; }
            CONN(wv.x) CONN(wv.y) CONN(wv.z) CONN(wv.w)
#undef CONN
        }
        out[(size_t)bs0 * F_ + f] = a0;
        out[(size_t)(bs0 + 1) * F_ + f] = a1;
    }
}

extern "C" void kernel_launch(void* const* d_in, const int* in_sizes, int n_in,
                              void* d_out, int out_size, void* d_ws, size_t ws_size,
                              hipStream_t stream) {
    const float* up   = (const float*)d_in[0];  // up_facts   [B,S,F]
    const float* enc  = (const float*)d_in[1];  // down_encoder [F,D]
    const float* dec  = (const float*)d_in[2];  // up_decoder [D,F]
    // d_in[3] = i_indices, unused: i[m] = m >> 4 by construction
    const int*   jidx = (const int*)d_in[4];    // j_indices  [M]
    float*       out  = (float*)d_out;

    size_t decC_bytes    = (size_t)NCHUNK * F_ * CDIM * sizeof(unsigned short); // 25.2 MB
    size_t partial_bytes = (size_t)NCHUNK * M_ * sizeof(float);                 // 8 MB
    unsigned short* decC    = (unsigned short*)d_ws;
    float*          partial = (float*)((char*)d_ws + decC_bytes);
    unsigned int*   packed  = (unsigned int*)((char*)d_ws + decC_bytes + partial_bytes);

    k_transpose_chunked<<<dim3(F_ / 64, D_ / 64), 256, 0, stream>>>(dec, decC);
    k_values_chunked<<<NCHUNK * (M_ / CPB), 256, 0, stream>>>(enc, decC, jidx, partial);
    k_pack<<<M_ / 256, 256, 0, stream>>>(partial, jidx, packed);
    k_out<<<BS_, 1024, 0, stream>>>(up, packed, out);
}

// Round 6
// 227.359 us; speedup vs baseline: 1.0084x; 1.0084x over previous
//
#include <hip/hip_runtime.h>
#include <hip/hip_bf16.h>

#define F_ 16384
#define D_ 768
#define C_ 16
#define BS_ 512
#define M_ (F_*C_)
#define NCHUNK 8
#define CDIM 96           // dims per chunk (NCHUNK*CDIM = D_)
#define CPB 512           // connections per k_values block
#define FPB (CPB/C_)      // 32 features per block

static __device__ __forceinline__ float bf2f(unsigned short u) {
    return __uint_as_float(((unsigned int)u) << 16);
}
static __device__ __forceinline__ unsigned short f2bf(float f) {
    return __bfloat16_as_ushort(__float2bfloat16(f));
}

// dot of two bf16 pairs (packed in uint) + fp32 acc, single-instruction path.
#if __has_builtin(__builtin_amdgcn_fdot2_f32_bf16)
typedef __bf16 v2bf __attribute__((ext_vector_type(2)));
static __device__ __forceinline__ float dot2bf(unsigned int e, unsigned int g, float acc) {
    return __builtin_amdgcn_fdot2_f32_bf16(__builtin_bit_cast(v2bf, e),
                                           __builtin_bit_cast(v2bf, g), acc, false);
}
#else
static __device__ __forceinline__ float dot2bf(unsigned int e, unsigned int g, float acc) {
    acc += __uint_as_float(e << 16) * __uint_as_float(g << 16);
    acc += __uint_as_float(e & 0xffff0000u) * __uint_as_float(g & 0xffff0000u);
    return acc;
}
#endif

// ---------------------------------------------------------------------------
// Transpose + downconvert: up_decoder fp32 [D, F] -> decC bf16 chunk-major
// [NCHUNK][F][CDIM]. Tile = 64 f x 96 d (one full chunk) so every output
// row segment (192 B) is stored contiguously. float4 global loads.
// ---------------------------------------------------------------------------
__global__ __launch_bounds__(256) void k_transpose96(const float* __restrict__ in,
                                                     unsigned short* __restrict__ decC) {
    __shared__ float tile[96][65];      // 24.4 KB, +1 pad (65 = 1 mod 32)
    int fbase = blockIdx.x * 64;
    int c     = blockIdx.y;             // chunk = d block of 96
    const float* src = in + (size_t)c * CDIM * F_ + fbase;
#pragma unroll
    for (int k = 0; k < 6; ++k) {
        int slot = threadIdx.x + k * 256;     // 0..1535
        int d  = slot >> 4;                   // 0..95
        int f4 = slot & 15;
        float4 v = *(const float4*)(src + (size_t)d * F_ + f4 * 4);
        tile[d][f4 * 4 + 0] = v.x;
        tile[d][f4 * 4 + 1] = v.y;
        tile[d][f4 * 4 + 2] = v.z;
        tile[d][f4 * 4 + 3] = v.w;
    }
    __syncthreads();
#pragma unroll
    for (int k = 0; k < 6; ++k) {
        int slot = threadIdx.x + k * 256;     // 0..1535 = 64 f x 24 dgroups
        int f  = slot / 24;
        int dg = slot - f * 24;
        float v0 = tile[4 * dg + 0][f];
        float v1 = tile[4 * dg + 1][f];
        float v2 = tile[4 * dg + 2][f];
        float v3 = tile[4 * dg + 3][f];
        uint2 p;
        p.x = ((unsigned int)f2bf(v1) << 16) | (unsigned int)f2bf(v0);
        p.y = ((unsigned int)f2bf(v3) << 16) | (unsigned int)f2bf(v2);
        *(uint2*)(decC + ((size_t)c * F_ + fbase + f) * CDIM + 4 * dg) = p;
    }
}

// ---------------------------------------------------------------------------
// Pre-pack up rows for k_out: upP[pair][f] = bf16(up[2p][f]) | bf16(up[2p+1][f])<<16
// Fully coalesced; halves k_out staging bytes and removes its convert VALU.
// ---------------------------------------------------------------------------
__global__ __launch_bounds__(256) void k_up_pack(const float* __restrict__ up,
                                                 unsigned int* __restrict__ upP) {
    size_t idx = (size_t)blockIdx.x * 256 + threadIdx.x;   // uint4 slot
    int pair = (int)(idx >> 12);            // 4096 uint4 per pair
    int f4   = (int)(idx & 4095);
    const float4* r0 = (const float4*)(up + (size_t)(2 * pair) * F_);
    const float4* r1 = (const float4*)(up + (size_t)(2 * pair + 1) * F_);
    float4 a = r0[f4];
    float4 b = r1[f4];
    uint4 p;
    p.x = ((unsigned int)f2bf(b.x) << 16) | (unsigned int)f2bf(a.x);
    p.y = ((unsigned int)f2bf(b.y) << 16) | (unsigned int)f2bf(a.y);
    p.z = ((unsigned int)f2bf(b.z) << 16) | (unsigned int)f2bf(a.z);
    p.w = ((unsigned int)f2bf(b.w) << 16) | (unsigned int)f2bf(a.w);
    ((uint4*)(upP + (size_t)pair * F_))[f4] = p;
}

// ---------------------------------------------------------------------------
// Chunked values. partial[c][m] = dot(enc[f(m),c*96..+96), decC[c][j(m)]).
// blockIdx&7 = chunk (XCD-affine). 512 conns/block, enc slice bf16 in 6 KB
// LDS. 8-lane group per connection, 12 dims/lane (uint4+uint2 gather).
// Depth-3 pipeline (6 VMEM in flight); 6 x v_dot2_f32_bf16 per iter.
// ---------------------------------------------------------------------------
__global__ __launch_bounds__(256, 8) void k_values_chunked(const float* __restrict__ enc,
                                                           const unsigned short* __restrict__ decC,
                                                           const int* __restrict__ jidx,
                                                           float* __restrict__ partial) {
    __shared__ unsigned short encS[FPB * CDIM];   // 32 x 96 bf16 = 6 KB
    int chunk = blockIdx.x & 7;
    int mblk  = blockIdx.x >> 3;
    int m0 = mblk * CPB;
    int f0 = mblk * FPB;

    {   // Stage enc[f0..f0+32)[chunk*96..+96) fp32 -> bf16 LDS.
        const float* eb = enc + (size_t)f0 * D_ + chunk * CDIM;
#pragma unroll
        for (int k = 0; k < 3; ++k) {
            int idx = threadIdx.x + k * 256;     // 768 float4 slots = 32 x 24
            int row = idx / 24;
            int col = idx - row * 24;
            float4 v = *(const float4*)(eb + (size_t)row * D_ + col * 4);
            uint2 p;
            p.x = ((unsigned int)f2bf(v.y) << 16) | (unsigned int)f2bf(v.x);
            p.y = ((unsigned int)f2bf(v.w) << 16) | (unsigned int)f2bf(v.z);
            *(uint2*)(encS + row * CDIM + col * 4) = p;
        }
    }
    __syncthreads();

    int lane = threadIdx.x & 63;
    int w    = threadIdx.x >> 6;        // wave 0..3
    int sub  = lane & 7;                // dim-group within connection
    int cg   = lane >> 3;               // connection within wave-iter
    const unsigned short* db = decC + (size_t)chunk * F_ * CDIM;

#define JIDX(i) jidx[m0 + (((i) * 4 + w) << 3) + cg]
    int j;
    j = JIDX(0);
    const char* q0 = (const char*)(db + (size_t)j * CDIM) + sub * 24;
    uint4 a0 = *(const uint4*)q0;  uint2 b0 = *(const uint2*)(q0 + 16);
    j = JIDX(1);
    const char* q1 = (const char*)(db + (size_t)j * CDIM) + sub * 24;
    uint4 a1 = *(const uint4*)q1;  uint2 b1 = *(const uint2*)(q1 + 16);
    j = JIDX(2);
    const char* q2 = (const char*)(db + (size_t)j * CDIM) + sub * 24;
    uint4 a2 = *(const uint4*)q2;  uint2 b2 = *(const uint2*)(q2 + 16);
    int jn = JIDX(3);

#pragma unroll 4
    for (int i = 0; i < 16; ++i) {
        uint4 na; uint2 nb;
        if (i + 3 < 16) {
            const char* qn = (const char*)(db + (size_t)jn * CDIM) + sub * 24;
            na = *(const uint4*)qn;
            nb = *(const uint2*)(qn + 16);
        }
        if (i + 4 < 16)
            jn = JIDX(i + 4);

        int qq = i * 4 + w;                    // 0..63
        int fl = qq >> 1;                      // f_local 0..31
        const unsigned short* ep = encS + fl * CDIM + sub * 12;
        uint2 e0 = *(const uint2*)ep;          // dims 0-3
        uint2 e1 = *(const uint2*)(ep + 4);    // dims 4-7
        uint2 e2 = *(const uint2*)(ep + 8);    // dims 8-11
        float acc = 0.f;
        acc = dot2bf(e0.x, a0.x, acc);
        acc = dot2bf(e0.y, a0.y, acc);
        acc = dot2bf(e1.x, a0.z, acc);
        acc = dot2bf(e1.y, a0.w, acc);
        acc = dot2bf(e2.x, b0.x, acc);
        acc = dot2bf(e2.y, b0.y, acc);
        acc += __shfl_xor(acc, 1, 64);
        acc += __shfl_xor(acc, 2, 64);
        acc += __shfl_xor(acc, 4, 64);
        if (sub == 0)
            partial[(size_t)chunk * M_ + m0 + (qq << 3) + cg] = acc;
        a0 = a1; b0 = b1; a1 = a2; b1 = b2; a2 = na; b2 = nb;
    }
#undef JIDX
}

// ---------------------------------------------------------------------------
// Sum the 8 chunk-partials and emit packed stream: (bf16 value << 16) | u16 j.
// ---------------------------------------------------------------------------
__global__ __launch_bounds__(256) void k_pack(const float* __restrict__ partial,
                                              const int* __restrict__ jidx,
                                              unsigned int* __restrict__ packed) {
    int m = blockIdx.x * 256 + threadIdx.x;
    float s = 0.f;
#pragma unroll
    for (int c = 0; c < NCHUNK; ++c)
        s += partial[(size_t)c * M_ + m];
    packed[m] = ((unsigned int)f2bf(s) << 16) | (unsigned int)jidx[m];
}

// ---------------------------------------------------------------------------
// out[bs,f] = sum over 16 connections of up[bs,j]*v.
// Block = (bs pair, f half): 512 blocks x 512 threads, 64 KB LDS -> 2
// blocks/CU. Staging is a raw uint4 copy of the pre-packed pair row; one
// ds_read_b32 serves both bs rows. Connection decode: v_perm packs two
// connections' (v,v) and the gathered (r,r) pairs -> v_dot2_f32_bf16.
// ---------------------------------------------------------------------------
__global__ __launch_bounds__(512) void k_out(const unsigned int* __restrict__ upP,
                                             const unsigned int* __restrict__ packed,
                                             float* __restrict__ out) {
    __shared__ unsigned int rowp[F_];   // 64 KB
    int pair = blockIdx.x >> 1;
    int half = blockIdx.x & 1;
    int bs0  = pair << 1;
    const uint4* src = (const uint4*)(upP + (size_t)pair * F_);
#pragma unroll
    for (int k = 0; k < 8; ++k) {
        int idx = threadIdx.x + k * 512;       // uint4 index, 4096 total
        ((uint4*)rowp)[idx] = src[idx];
    }
    __syncthreads();
    int f0 = half << 13;                       // 0 or 8192
#pragma unroll 4
    for (int it = 0; it < 16; ++it) {
        int f = f0 + threadIdx.x + it * 512;
        const uint4* sp = (const uint4*)(packed + ((size_t)f << 4));
        float a0 = 0.f, a1 = 0.f;
#pragma unroll
        for (int q = 0; q < 4; ++q) {
            uint4 wv = sp[q];
            // two connections per step: (x,y) then (z,w)
#define CONN2(wx, wy) {                                                     \
            unsigned int px = rowp[(wx) & 0xffffu];                         \
            unsigned int py = rowp[(wy) & 0xffffu];                         \
            unsigned int ev = __builtin_amdgcn_perm((wy), (wx), 0x07060302u); \
            unsigned int g0 = __builtin_amdgcn_perm(py, px, 0x05040100u);   \
            unsigned int g1 = __builtin_amdgcn_perm(py, px, 0x07060302u);   \
            a0 = dot2bf(ev, g0, a0);                                        \
            a1 = dot2bf(ev, g1, a1); }
            CONN2(wv.x, wv.y)
            CONN2(wv.z, wv.w)
#undef CONN2
        }
        out[(size_t)bs0 * F_ + f] = a0;
        out[(size_t)(bs0 + 1) * F_ + f] = a1;
    }
}

extern "C" void kernel_launch(void* const* d_in, const int* in_sizes, int n_in,
                              void* d_out, int out_size, void* d_ws, size_t ws_size,
                              hipStream_t stream) {
    const float* up   = (const float*)d_in[0];  // up_facts   [B,S,F]
    const float* enc  = (const float*)d_in[1];  // down_encoder [F,D]
    const float* dec  = (const float*)d_in[2];  // up_decoder [D,F]
    // d_in[3] = i_indices, unused: i[m] = m >> 4 by construction
    const int*   jidx = (const int*)d_in[4];    // j_indices  [M]
    float*       out  = (float*)d_out;

    size_t decC_bytes    = (size_t)NCHUNK * F_ * CDIM * sizeof(unsigned short); // 25,165,824
    size_t partial_bytes = (size_t)NCHUNK * M_ * sizeof(float);                 //  8,388,608
    size_t packed_bytes  = (size_t)M_ * sizeof(unsigned int);                   //  1,048,576
    unsigned short* decC    = (unsigned short*)d_ws;
    float*          partial = (float*)((char*)d_ws + decC_bytes);
    unsigned int*   packed  = (unsigned int*)((char*)d_ws + decC_bytes + partial_bytes);
    unsigned int*   upP     = (unsigned int*)((char*)d_ws + decC_bytes + partial_bytes + packed_bytes);
    // total = 51,380,224 B -- identical to the round-1 footprint that fit.

    k_transpose96<<<dim3(F_ / 64, NCHUNK), 256, 0, stream>>>(dec, decC);
    k_up_pack<<<(BS_ / 2) * (F_ / 4) / 256, 256, 0, stream>>>(up, upP);
    k_values_chunked<<<NCHUNK * (M_ / CPB), 256, 0, stream>>>(enc, decC, jidx, partial);
    k_pack<<<M_ / 256, 256, 0, stream>>>(partial, jidx, packed);
    k_out<<<BS_, 512, 0, stream>>>(upP, packed, out);
}